// Round 6
// baseline (605.949 us; speedup 1.0000x reference)
//
#include <hip/hip_runtime.h>
#include <hip/hip_bf16.h>
#include <stdint.h>

// F8Linear: y[m,n] = sum_k x[m,k] * (w_f8[n,k] * s) + bias[n]
// M=1024, N=14336, K=4096.
//
// R6 WORLD MODEL (fits all 5 prior rounds with one mechanism): the harness
// environment materializes jax-bf16 arrays as FLOAT32 numpy containers.
// => x arrives as f32 [1024][4096]; d_out is an f32 container [1024][14336].
// Detector hedges the alternative world: if x is a genuine bf16 buffer
// (flag=0), both the A-staging AND the output dtype switch to bf16.
//
// Core: R2/R3-probe-verified 128x128 tile, BK=32, mfma_f32_16x16x32_bf16,
// register->padded-LDS staging, register prefetch, scale in epilogue.

#define IN_F   4096
#define OUT_F  14336
#define M_TOT  1024

#define BM 128
#define BN 128
#define BK 32
#define APAD 40
#define BPAD 40
#define KTILES (IN_F / BK)   // 128

typedef __bf16  bf16x8 __attribute__((ext_vector_type(8)));
typedef __bf16  bf16x4 __attribute__((ext_vector_type(4)));
typedef float   f32x4  __attribute__((ext_vector_type(4)));

// bf16-valued f32 words have low16 == 0; genuine-bf16 pairs never do (over
// 1024 normal dwords). flag=1 -> f32 containers for bf16-typed tensors.
__global__ void detect_x_dtype(const uint32_t* __restrict__ xb,
                               int* __restrict__ flag) {
    if (threadIdx.x == 0 && blockIdx.x == 0) {
        int allzero = 1;
        for (int i = 0; i < 1024; ++i)
            if (xb[i] & 0xFFFFu) { allzero = 0; break; }
        *flag = allzero;
    }
}

__global__ __launch_bounds__(256) void f8linear_kernel(
    const void*  __restrict__ xraw,    // [M_TOT][IN_F], container per flag
    const float* __restrict__ wq,      // [OUT_F][IN_F]
    const float* __restrict__ w_scale, // [1]
    const float* __restrict__ bias,    // [OUT_F]
    void*        __restrict__ yraw,    // [M_TOT][OUT_F], container per flag
    const int*   __restrict__ flag_p)
{
    __shared__ __align__(16) __bf16 As[BM * APAD];  // 10 KiB
    __shared__ __align__(16) __bf16 Bs[BN * BPAD];  // 10 KiB

    const int f32w = (*flag_p != 0);     // wave-uniform; poison(0xAA..)!=0 -> f32 world

    const int t    = threadIdx.x;        // 0..255
    const int lane = t & 63;
    const int wv   = t >> 6;             // wave 0..3
    const int wm   = wv >> 1;            // 0..1 (M half)
    const int wn   = wv & 1;             // 0..1 (N half)
    const int lidx = lane & 15;
    const int q    = lane >> 4;          // 0..3

    // XCD-aware remap (bijection over 896): each XCD owns 14 N-tiles, M fastest.
    const int flat = blockIdx.x;
    const int xcd  = flat & 7;
    const int slot = flat >> 3;              // 0..111
    const int ni   = xcd * 14 + (slot >> 3); // 0..111
    const int mi   = slot & 7;               // 0..7
    const int m0   = mi * BM;
    const int n0   = ni * BN;

    const float scale = w_scale[0];

    const float*  xf = (const float*)xraw;
    const __bf16* xh = (const __bf16*)xraw;

    // ---- A staging mappings ----
    // f32 world: 4x f32x4 loads; row = t>>3 + i*32, col = (t&7)*4
    const int af_row = t >> 3;       // 0..31
    const int af_col = (t & 7) * 4;  // 0,4..28
    // bf16 world: 2x bf16x8 loads; slot s = i*256+t -> row s>>2, cg s&3
    int ah_row[2], ah_cg[2];
    #pragma unroll
    for (int i = 0; i < 2; ++i) {
        const int s = i * 256 + t;
        ah_row[i] = s >> 2;
        ah_cg[i]  = s & 3;
    }

    // ---- B staging: 4x f32x4 loads; row = t>>3 + i*32, col = (t&7)*4 ----
    const int b_row = t >> 3;
    const int b_col = (t & 7) * 4;

    const f32x4 zero4 = {0.f, 0.f, 0.f, 0.f};
    f32x4 acc[4][4];
    #pragma unroll
    for (int i = 0; i < 4; ++i)
        #pragma unroll
        for (int j = 0; j < 4; ++j)
            acc[i][j] = zero4;

    // prologue: prefetch tile kt=0
    f32x4  aregf[4];
    bf16x8 aregh[2];
    f32x4  breg[4];
    if (f32w) {
        #pragma unroll
        for (int i = 0; i < 4; ++i)
            aregf[i] = *reinterpret_cast<const f32x4*>(
                xf + (size_t)(m0 + af_row + i * 32) * IN_F + af_col);
    } else {
        #pragma unroll
        for (int i = 0; i < 2; ++i)
            aregh[i] = *reinterpret_cast<const bf16x8*>(
                xh + (size_t)(m0 + ah_row[i]) * IN_F + ah_cg[i] * 8);
    }
    #pragma unroll
    for (int i = 0; i < 4; ++i)
        breg[i] = *reinterpret_cast<const f32x4*>(
            wq + (size_t)(n0 + i * 32 + b_row) * IN_F + b_col);

    for (int kt = 0; kt < KTILES; ++kt) {
        const int k0 = kt * BK;

        // stage registers -> LDS (cvt f32->bf16 where needed; x,w values are
        // bf16/e4m3-exact so the casts are lossless)
        if (f32w) {
            #pragma unroll
            for (int i = 0; i < 4; ++i) {
                bf16x4 pk;
                pk[0] = (__bf16)aregf[i][0];
                pk[1] = (__bf16)aregf[i][1];
                pk[2] = (__bf16)aregf[i][2];
                pk[3] = (__bf16)aregf[i][3];
                *reinterpret_cast<bf16x4*>(As + (af_row + i * 32) * APAD + af_col) = pk;
            }
        } else {
            #pragma unroll
            for (int i = 0; i < 2; ++i)
                *reinterpret_cast<bf16x8*>(As + ah_row[i] * APAD + ah_cg[i] * 8) = aregh[i];
        }
        #pragma unroll
        for (int i = 0; i < 4; ++i) {
            bf16x4 pk;
            pk[0] = (__bf16)breg[i][0];
            pk[1] = (__bf16)breg[i][1];
            pk[2] = (__bf16)breg[i][2];
            pk[3] = (__bf16)breg[i][3];
            *reinterpret_cast<bf16x4*>(Bs + (i * 32 + b_row) * BPAD + b_col) = pk;
        }

        __syncthreads();

        // prefetch next tile into regs (overlaps HBM latency with MFMA)
        if (kt + 1 < KTILES) {
            const int k1 = k0 + BK;
            if (f32w) {
                #pragma unroll
                for (int i = 0; i < 4; ++i)
                    aregf[i] = *reinterpret_cast<const f32x4*>(
                        xf + (size_t)(m0 + af_row + i * 32) * IN_F + k1 + af_col);
            } else {
                #pragma unroll
                for (int i = 0; i < 2; ++i)
                    aregh[i] = *reinterpret_cast<const bf16x8*>(
                        xh + (size_t)(m0 + ah_row[i]) * IN_F + k1 + ah_cg[i] * 8);
            }
            #pragma unroll
            for (int i = 0; i < 4; ++i)
                breg[i] = *reinterpret_cast<const f32x4*>(
                    wq + (size_t)(n0 + i * 32 + b_row) * IN_F + k1 + b_col);
        }

        // fragments: A[m=lidx][k=q*8+j], B[n=lidx][k=q*8+j] per 16x16 tile
        bf16x8 afr[4], bfr[4];
        #pragma unroll
        for (int mt = 0; mt < 4; ++mt) {
            const int row = wm * 64 + mt * 16 + lidx;
            afr[mt] = *reinterpret_cast<const bf16x8*>(As + row * APAD + q * 8);
        }
        #pragma unroll
        for (int nt = 0; nt < 4; ++nt) {
            const int row = wn * 64 + nt * 16 + lidx;
            bfr[nt] = *reinterpret_cast<const bf16x8*>(Bs + row * BPAD + q * 8);
        }

        #pragma unroll
        for (int mt = 0; mt < 4; ++mt)
            #pragma unroll
            for (int nt = 0; nt < 4; ++nt)
                acc[mt][nt] = __builtin_amdgcn_mfma_f32_16x16x32_bf16(
                    afr[mt], bfr[nt], acc[mt][nt], 0, 0, 0);

        __syncthreads();
    }

    // ---- epilogue: y = acc*scale + bias ----
    // C/D layout (R3-probe-verified): n = lane&15, m = q*4 + reg
    float bv[4];
    #pragma unroll
    for (int nt = 0; nt < 4; ++nt)
        bv[nt] = bias[n0 + wn * 64 + nt * 16 + lidx];

    if (f32w) {
        float* yf = (float*)yraw;
        #pragma unroll
        for (int mt = 0; mt < 4; ++mt) {
            #pragma unroll
            for (int r = 0; r < 4; ++r) {
                const int m = m0 + wm * 64 + mt * 16 + q * 4 + r;
                float* yp = yf + (size_t)m * OUT_F + n0 + wn * 64 + lidx;
                #pragma unroll
                for (int nt = 0; nt < 4; ++nt)
                    yp[nt * 16] = acc[mt][nt][r] * scale + bv[nt];
            }
        }
    } else {
        __bf16* yh = (__bf16*)yraw;
        #pragma unroll
        for (int mt = 0; mt < 4; ++mt) {
            #pragma unroll
            for (int r = 0; r < 4; ++r) {
                const int m = m0 + wm * 64 + mt * 16 + q * 4 + r;
                __bf16* yp = yh + (size_t)m * OUT_F + n0 + wn * 64 + lidx;
                #pragma unroll
                for (int nt = 0; nt < 4; ++nt)
                    yp[nt * 16] = (__bf16)(acc[mt][nt][r] * scale + bv[nt]);
            }
        }
    }
}

extern "C" void kernel_launch(void* const* d_in, const int* in_sizes, int n_in,
                              void* d_out, int out_size, void* d_ws, size_t ws_size,
                              hipStream_t stream) {
    // Assign inputs by distinct element-count signature (order-immune):
    const void* px = nullptr; const void* pw = nullptr;
    const void* ps = nullptr; const void* pb = nullptr;
    for (int i = 0; i < n_in; ++i) {
        const long sz = in_sizes[i];
        if      (sz == (long)M_TOT * IN_F) px = d_in[i];
        else if (sz == (long)OUT_F * IN_F) pw = d_in[i];
        else if (sz == 1)                  ps = d_in[i];
        else if (sz == OUT_F)              pb = d_in[i];
    }
    if (!px) px = d_in[0];
    if (!pw) pw = d_in[1];
    if (!ps) ps = d_in[2];
    if (!pb) pb = d_in[3];

    int* flag = (int*)d_ws;   // rewritten by detector every launch

    detect_x_dtype<<<1, 64, 0, stream>>>((const uint32_t*)px, flag);

    const int grid = (M_TOT / BM) * (OUT_F / BN);   // 896
    f8linear_kernel<<<grid, 256, 0, stream>>>(
        px, (const float*)pw, (const float*)ps, (const float*)pb,
        d_out, flag);
}

// Round 7
// 550.412 us; speedup vs baseline: 1.1009x; 1.1009x over previous
//
#include <hip/hip_runtime.h>
#include <hip/hip_bf16.h>
#include <stdint.h>

// F8Linear: y[m,n] = sum_k x[m,k] * (w_f8[n,k] * s) + bias[n]
// M=1024, N=14336, K=4096.
// World model (R6-verified): bf16-typed tensors travel in f32 containers
// (x input, y output). w, scale, bias are genuine f32.
//
// R7: (1) parallel detector (was 290us serial); (2) pre-convert w,x to bf16
// in d_ws (memory-bound, ~60us) so the GEMM is pure-bf16; (3) GEMM = exact
// m97-verified structure: global_load_lds width=16 both operands, linear LDS,
// 128x128 tile, BK=32, mfma_f32_16x16x32_bf16. Fallback to R6 kernel if
// ws_size is too small.

#define IN_F   4096
#define OUT_F  14336
#define M_TOT  1024

#define BM 128
#define BN 128
#define BK 32
#define KTILES (IN_F / BK)   // 128

typedef __bf16  bf16x8 __attribute__((ext_vector_type(8)));
typedef __bf16  bf16x4 __attribute__((ext_vector_type(4)));
typedef float   f32x4  __attribute__((ext_vector_type(4)));

__device__ __forceinline__ void async_copy16(const void* g, void* l) {
    __builtin_amdgcn_global_load_lds(
        (const __attribute__((address_space(1))) void*)g,
        (__attribute__((address_space(3))) void*)l,
        16, 0, 0);
}

// ---- detector: bf16-valued f32 words have low16 == 0 over 1024 dwords ----
__global__ void detect_x_dtype(const uint32_t* __restrict__ xb,
                               int* __restrict__ flag) {
    __shared__ int any_low;
    if (threadIdx.x == 0) any_low = 0;
    __syncthreads();
    uint32_t bad = 0;
    for (int i = threadIdx.x; i < 1024; i += 256) bad |= (xb[i] & 0xFFFFu);
    if (bad) atomicOr(&any_low, 1);
    __syncthreads();
    if (threadIdx.x == 0) *flag = (any_low == 0) ? 1 : 0;
}

// ---- cvt passes ----
// w: 58,720,256 f32 -> bf16. 14,680,064 vec4; 3584*256 threads x 16 iters.
__global__ __launch_bounds__(256) void cvt_w_kernel(
    const f32x4* __restrict__ in, bf16x4* __restrict__ out) {
    const int stride = 3584 * 256;
    for (int i = blockIdx.x * 256 + threadIdx.x; i < 14680064; i += stride) {
        f32x4 v = in[i];
        bf16x4 o;
        o[0] = (__bf16)v[0]; o[1] = (__bf16)v[1];
        o[2] = (__bf16)v[2]; o[3] = (__bf16)v[3];
        out[i] = o;
    }
}

// x: 4,194,304 elems -> bf16 (cvt from f32 world, or copy bf16 world).
__global__ __launch_bounds__(256) void cvt_x_kernel(
    const void* __restrict__ xraw, bf16x4* __restrict__ out,
    const int* __restrict__ flag) {
    const int f32w = (*flag != 0);
    const int stride = 1024 * 256;
    if (f32w) {
        const f32x4* in = (const f32x4*)xraw;
        for (int i = blockIdx.x * 256 + threadIdx.x; i < 1048576; i += stride) {
            f32x4 v = in[i];
            bf16x4 o;
            o[0] = (__bf16)v[0]; o[1] = (__bf16)v[1];
            o[2] = (__bf16)v[2]; o[3] = (__bf16)v[3];
            out[i] = o;
        }
    } else {
        const bf16x4* in = (const bf16x4*)xraw;
        for (int i = blockIdx.x * 256 + threadIdx.x; i < 1048576; i += stride)
            out[i] = in[i];
    }
}

// ---- main GEMM: m97 structure, both operands bf16 via global_load_lds ----
__global__ __launch_bounds__(256) void gemm_bf16(
    const __bf16* __restrict__ xb,     // [M_TOT][IN_F] bf16 (in ws)
    const __bf16* __restrict__ wb,     // [OUT_F][IN_F] bf16 (in ws)
    const float*  __restrict__ w_scale,
    const float*  __restrict__ bias,
    void*         __restrict__ yraw,   // f32 or bf16 container per flag
    const int*    __restrict__ flag_p)
{
    __shared__ __align__(16) __bf16 As[BM * BK];   // 8 KiB linear
    __shared__ __align__(16) __bf16 Bs[BN * BK];   // 8 KiB linear

    const int f32w = (*flag_p != 0);

    const int t    = threadIdx.x;
    const int lane = t & 63;
    const int wv   = t >> 6;
    const int wm   = wv >> 1;
    const int wn   = wv & 1;
    const int lidx = lane & 15;
    const int q    = lane >> 4;

    // XCD-aware remap (bijection over 896): each XCD owns 14 N-tiles, M fastest.
    const int flat = blockIdx.x;
    const int xcd  = flat & 7;
    const int slot = flat >> 3;
    const int ni   = xcd * 14 + (slot >> 3);
    const int mi   = slot & 7;
    const int m0   = mi * BM;
    const int n0   = ni * BN;

    const float scale = w_scale[0];

    // DMA slots: s in {t, 256+t}; row = s>>2, cg = s&3; LDS linear at s*8 elems.
    const int s0 = t, s1 = 256 + t;
    const __bf16* ga0 = xb + (size_t)(m0 + (s0 >> 2)) * IN_F + (s0 & 3) * 8;
    const __bf16* ga1 = xb + (size_t)(m0 + (s1 >> 2)) * IN_F + (s1 & 3) * 8;
    const __bf16* gb0 = wb + (size_t)(n0 + (s0 >> 2)) * IN_F + (s0 & 3) * 8;
    const __bf16* gb1 = wb + (size_t)(n0 + (s1 >> 2)) * IN_F + (s1 & 3) * 8;
    __bf16* la0 = As + s0 * 8;
    __bf16* la1 = As + s1 * 8;
    __bf16* lb0 = Bs + s0 * 8;
    __bf16* lb1 = Bs + s1 * 8;

    const f32x4 zero4 = {0.f, 0.f, 0.f, 0.f};
    f32x4 acc[4][4];
    #pragma unroll
    for (int i = 0; i < 4; ++i)
        #pragma unroll
        for (int j = 0; j < 4; ++j)
            acc[i][j] = zero4;

    for (int kt = 0; kt < KTILES; ++kt) {
        async_copy16(ga0, la0);
        async_copy16(ga1, la1);
        async_copy16(gb0, lb0);
        async_copy16(gb1, lb1);
        ga0 += BK; ga1 += BK; gb0 += BK; gb1 += BK;

        __syncthreads();   // drains DMA (vmcnt) before ds_read

        bf16x8 afr[4], bfr[4];
        #pragma unroll
        for (int mt = 0; mt < 4; ++mt) {
            const int row = wm * 64 + mt * 16 + lidx;
            afr[mt] = *reinterpret_cast<const bf16x8*>(As + row * BK + q * 8);
        }
        #pragma unroll
        for (int nt = 0; nt < 4; ++nt) {
            const int row = wn * 64 + nt * 16 + lidx;
            bfr[nt] = *reinterpret_cast<const bf16x8*>(Bs + row * BK + q * 8);
        }

        #pragma unroll
        for (int mt = 0; mt < 4; ++mt)
            #pragma unroll
            for (int nt = 0; nt < 4; ++nt)
                acc[mt][nt] = __builtin_amdgcn_mfma_f32_16x16x32_bf16(
                    afr[mt], bfr[nt], acc[mt][nt], 0, 0, 0);

        __syncthreads();   // WAR: LDS reuse by next iter's DMA
    }

    // epilogue (R3-probe-verified C/D layout: n = lane&15, m = q*4 + reg)
    float bv[4];
    #pragma unroll
    for (int nt = 0; nt < 4; ++nt)
        bv[nt] = bias[n0 + wn * 64 + nt * 16 + lidx];

    if (f32w) {
        float* yf = (float*)yraw;
        #pragma unroll
        for (int mt = 0; mt < 4; ++mt)
            #pragma unroll
            for (int r = 0; r < 4; ++r) {
                const int m = m0 + wm * 64 + mt * 16 + q * 4 + r;
                float* yp = yf + (size_t)m * OUT_F + n0 + wn * 64 + lidx;
                #pragma unroll
                for (int nt = 0; nt < 4; ++nt)
                    yp[nt * 16] = acc[mt][nt][r] * scale + bv[nt];
            }
    } else {
        __bf16* yh = (__bf16*)yraw;
        #pragma unroll
        for (int mt = 0; mt < 4; ++mt)
            #pragma unroll
            for (int r = 0; r < 4; ++r) {
                const int m = m0 + wm * 64 + mt * 16 + q * 4 + r;
                __bf16* yp = yh + (size_t)m * OUT_F + n0 + wn * 64 + lidx;
                #pragma unroll
                for (int nt = 0; nt < 4; ++nt)
                    yp[nt * 16] = (__bf16)(acc[mt][nt][r] * scale + bv[nt]);
            }
    }
}

// ---- fallback (R6 kernel): used only if ws_size can't hold cvt buffers ----
__global__ __launch_bounds__(256) void f8linear_fallback(
    const void*  __restrict__ xraw,
    const float* __restrict__ wq,
    const float* __restrict__ w_scale,
    const float* __restrict__ bias,
    void*        __restrict__ yraw,
    const int*   __restrict__ flag_p)
{
    __shared__ __align__(16) __bf16 As[BM * 40];
    __shared__ __align__(16) __bf16 Bs[BN * 40];

    const int f32w = (*flag_p != 0);
    const int t    = threadIdx.x;
    const int lane = t & 63;
    const int wv   = t >> 6;
    const int wm   = wv >> 1;
    const int wn   = wv & 1;
    const int lidx = lane & 15;
    const int q    = lane >> 4;

    const int flat = blockIdx.x;
    const int xcd  = flat & 7;
    const int slot = flat >> 3;
    const int ni   = xcd * 14 + (slot >> 3);
    const int mi   = slot & 7;
    const int m0   = mi * BM;
    const int n0   = ni * BN;

    const float scale = w_scale[0];
    const float*  xf = (const float*)xraw;
    const __bf16* xh = (const __bf16*)xraw;

    const int af_row = t >> 3;
    const int af_col = (t & 7) * 4;
    int ah_row[2], ah_cg[2];
    #pragma unroll
    for (int i = 0; i < 2; ++i) {
        const int s = i * 256 + t;
        ah_row[i] = s >> 2;
        ah_cg[i]  = s & 3;
    }
    const int b_row = t >> 3;
    const int b_col = (t & 7) * 4;

    const f32x4 zero4 = {0.f, 0.f, 0.f, 0.f};
    f32x4 acc[4][4];
    #pragma unroll
    for (int i = 0; i < 4; ++i)
        #pragma unroll
        for (int j = 0; j < 4; ++j)
            acc[i][j] = zero4;

    f32x4  aregf[4];
    bf16x8 aregh[2];
    f32x4  breg[4];
    if (f32w) {
        #pragma unroll
        for (int i = 0; i < 4; ++i)
            aregf[i] = *reinterpret_cast<const f32x4*>(
                xf + (size_t)(m0 + af_row + i * 32) * IN_F + af_col);
    } else {
        #pragma unroll
        for (int i = 0; i < 2; ++i)
            aregh[i] = *reinterpret_cast<const bf16x8*>(
                xh + (size_t)(m0 + ah_row[i]) * IN_F + ah_cg[i] * 8);
    }
    #pragma unroll
    for (int i = 0; i < 4; ++i)
        breg[i] = *reinterpret_cast<const f32x4*>(
            wq + (size_t)(n0 + i * 32 + b_row) * IN_F + b_col);

    for (int kt = 0; kt < KTILES; ++kt) {
        const int k0 = kt * BK;
        if (f32w) {
            #pragma unroll
            for (int i = 0; i < 4; ++i) {
                bf16x4 pk;
                pk[0] = (__bf16)aregf[i][0];
                pk[1] = (__bf16)aregf[i][1];
                pk[2] = (__bf16)aregf[i][2];
                pk[3] = (__bf16)aregf[i][3];
                *reinterpret_cast<bf16x4*>(As + (af_row + i * 32) * 40 + af_col) = pk;
            }
        } else {
            #pragma unroll
            for (int i = 0; i < 2; ++i)
                *reinterpret_cast<bf16x8*>(As + ah_row[i] * 40 + ah_cg[i] * 8) = aregh[i];
        }
        #pragma unroll
        for (int i = 0; i < 4; ++i) {
            bf16x4 pk;
            pk[0] = (__bf16)breg[i][0];
            pk[1] = (__bf16)breg[i][1];
            pk[2] = (__bf16)breg[i][2];
            pk[3] = (__bf16)breg[i][3];
            *reinterpret_cast<bf16x4*>(Bs + (i * 32 + b_row) * 40 + b_col) = pk;
        }
        __syncthreads();
        if (kt + 1 < KTILES) {
            const int k1 = k0 + BK;
            if (f32w) {
                #pragma unroll
                for (int i = 0; i < 4; ++i)
                    aregf[i] = *reinterpret_cast<const f32x4*>(
                        xf + (size_t)(m0 + af_row + i * 32) * IN_F + k1 + af_col);
            } else {
                #pragma unroll
                for (int i = 0; i < 2; ++i)
                    aregh[i] = *reinterpret_cast<const bf16x8*>(
                        xh + (size_t)(m0 + ah_row[i]) * IN_F + k1 + ah_cg[i] * 8);
            }
            #pragma unroll
            for (int i = 0; i < 4; ++i)
                breg[i] = *reinterpret_cast<const f32x4*>(
                    wq + (size_t)(n0 + i * 32 + b_row) * IN_F + k1 + b_col);
        }
        bf16x8 afr[4], bfr[4];
        #pragma unroll
        for (int mt = 0; mt < 4; ++mt) {
            const int row = wm * 64 + mt * 16 + lidx;
            afr[mt] = *reinterpret_cast<const bf16x8*>(As + row * 40 + q * 8);
        }
        #pragma unroll
        for (int nt = 0; nt < 4; ++nt) {
            const int row = wn * 64 + nt * 16 + lidx;
            bfr[nt] = *reinterpret_cast<const bf16x8*>(Bs + row * 40 + q * 8);
        }
        #pragma unroll
        for (int mt = 0; mt < 4; ++mt)
            #pragma unroll
            for (int nt = 0; nt < 4; ++nt)
                acc[mt][nt] = __builtin_amdgcn_mfma_f32_16x16x32_bf16(
                    afr[mt], bfr[nt], acc[mt][nt], 0, 0, 0);
        __syncthreads();
    }

    float bv[4];
    #pragma unroll
    for (int nt = 0; nt < 4; ++nt)
        bv[nt] = bias[n0 + wn * 64 + nt * 16 + lidx];

    if (f32w) {
        float* yf = (float*)yraw;
        #pragma unroll
        for (int mt = 0; mt < 4; ++mt)
            #pragma unroll
            for (int r = 0; r < 4; ++r) {
                const int m = m0 + wm * 64 + mt * 16 + q * 4 + r;
                float* yp = yf + (size_t)m * OUT_F + n0 + wn * 64 + lidx;
                #pragma unroll
                for (int nt = 0; nt < 4; ++nt)
                    yp[nt * 16] = acc[mt][nt][r] * scale + bv[nt];
            }
    } else {
        __bf16* yh = (__bf16*)yraw;
        #pragma unroll
        for (int mt = 0; mt < 4; ++mt)
            #pragma unroll
            for (int r = 0; r < 4; ++r) {
                const int m = m0 + wm * 64 + mt * 16 + q * 4 + r;
                __bf16* yp = yh + (size_t)m * OUT_F + n0 + wn * 64 + lidx;
                #pragma unroll
                for (int nt = 0; nt < 4; ++nt)
                    yp[nt * 16] = (__bf16)(acc[mt][nt][r] * scale + bv[nt]);
            }
    }
}

extern "C" void kernel_launch(void* const* d_in, const int* in_sizes, int n_in,
                              void* d_out, int out_size, void* d_ws, size_t ws_size,
                              hipStream_t stream) {
    const void* px = nullptr; const void* pw = nullptr;
    const void* ps = nullptr; const void* pb = nullptr;
    for (int i = 0; i < n_in; ++i) {
        const long sz = in_sizes[i];
        if      (sz == (long)M_TOT * IN_F) px = d_in[i];
        else if (sz == (long)OUT_F * IN_F) pw = d_in[i];
        else if (sz == 1)                  ps = d_in[i];
        else if (sz == OUT_F)              pb = d_in[i];
    }
    if (!px) px = d_in[0];
    if (!pw) pw = d_in[1];
    if (!ps) ps = d_in[2];
    if (!pb) pb = d_in[3];

    const size_t W_BYTES  = (size_t)OUT_F * IN_F * 2;   // 117,440,512
    const size_t X_OFF    = W_BYTES;
    const size_t X_BYTES  = (size_t)M_TOT * IN_F * 2;   // 8,388,608
    const size_t FLAG_OFF = X_OFF + X_BYTES;            // 125,829,120
    const int grid = (M_TOT / BM) * (OUT_F / BN);       // 896

    if (ws_size >= FLAG_OFF + 16) {
        __bf16* wbf  = (__bf16*)d_ws;
        __bf16* xbf  = (__bf16*)((char*)d_ws + X_OFF);
        int*    flag = (int*)((char*)d_ws + FLAG_OFF);

        detect_x_dtype<<<1, 256, 0, stream>>>((const uint32_t*)px, flag);
        cvt_w_kernel<<<3584, 256, 0, stream>>>((const f32x4*)pw, (bf16x4*)wbf);
        cvt_x_kernel<<<1024, 256, 0, stream>>>(px, (bf16x4*)xbf, flag);
        gemm_bf16<<<grid, 256, 0, stream>>>(
            xbf, wbf, (const float*)ps, (const float*)pb, d_out, flag);
    } else {
        int* flag = (int*)d_ws;
        detect_x_dtype<<<1, 256, 0, stream>>>((const uint32_t*)px, flag);
        f8linear_fallback<<<grid, 256, 0, stream>>>(
            px, (const float*)pw, (const float*)ps, (const float*)pb, d_out, flag);
    }
}

// Round 8
// 532.075 us; speedup vs baseline: 1.1388x; 1.0345x over previous
//
#include <hip/hip_runtime.h>
#include <hip/hip_bf16.h>
#include <stdint.h>

// F8Linear: y[m,n] = sum_k x[m,k] * (w_f8[n,k] * s) + bias[n]
// M=1024, N=14336, K=4096.
// World model (R6-verified): bf16-typed tensors travel in f32 containers
// (x input, y output). w, scale, bias are genuine f32.
//
// R8: (1) cvt_w rewritten for BW: f32x8 -> bf16x8, 16B/lane stores
//     (was ~1.8 TB/s, 8B stores).
//     (2) GEMM BK=64: 32 MFMAs per barrier pair (was 16), halves barrier
//     drains; XOR-swizzled 16B groups keep ds_read_b128 conflict-free.
// Core layout maps (R3-probe-verified) unchanged.

#define IN_F   4096
#define OUT_F  14336
#define M_TOT  1024

#define BM 128
#define BN 128
#define BK 64
#define KTILES (IN_F / BK)   // 64

typedef __bf16  bf16x8 __attribute__((ext_vector_type(8)));
typedef __bf16  bf16x4 __attribute__((ext_vector_type(4)));
typedef float   f32x4  __attribute__((ext_vector_type(4)));

__device__ __forceinline__ void async_copy16(const void* g, void* l) {
    __builtin_amdgcn_global_load_lds(
        (const __attribute__((address_space(1))) void*)g,
        (__attribute__((address_space(3))) void*)l,
        16, 0, 0);
}

// ---- detector: bf16-valued f32 words have low16 == 0 over 1024 dwords ----
__global__ void detect_x_dtype(const uint32_t* __restrict__ xb,
                               int* __restrict__ flag) {
    __shared__ int any_low;
    if (threadIdx.x == 0) any_low = 0;
    __syncthreads();
    uint32_t bad = 0;
    for (int i = threadIdx.x; i < 1024; i += 256) bad |= (xb[i] & 0xFFFFu);
    if (bad) atomicOr(&any_low, 1);
    __syncthreads();
    if (threadIdx.x == 0) *flag = (any_low == 0) ? 1 : 0;
}

// ---- cvt_w: 58,720,256 f32 -> bf16. vec8 granule: 7,340,032 iters.
// read 32B/lane (2x dwordx4), write 16B/lane (dwordx4). grid 3584 -> 8 iters.
__global__ __launch_bounds__(256) void cvt_w_kernel(
    const f32x4* __restrict__ in, bf16x8* __restrict__ out) {
    const int stride = 3584 * 256;
    for (int i = blockIdx.x * 256 + threadIdx.x; i < 7340032; i += stride) {
        f32x4 a = in[2 * i];
        f32x4 b = in[2 * i + 1];
        bf16x8 o;
        o[0] = (__bf16)a[0]; o[1] = (__bf16)a[1];
        o[2] = (__bf16)a[2]; o[3] = (__bf16)a[3];
        o[4] = (__bf16)b[0]; o[5] = (__bf16)b[1];
        o[6] = (__bf16)b[2]; o[7] = (__bf16)b[3];
        out[i] = o;
    }
}

// ---- cvt_x: 4,194,304 elems -> bf16 (cvt f32-world, copy bf16-world).
// vec8 granule: 524,288 = 2048 blocks x 256 threads x 1 iter.
__global__ __launch_bounds__(256) void cvt_x_kernel(
    const void* __restrict__ xraw, bf16x8* __restrict__ out,
    const int* __restrict__ flag) {
    const int f32w = (*flag != 0);
    const int i = blockIdx.x * 256 + threadIdx.x;   // 0..524287
    if (f32w) {
        const f32x4* in = (const f32x4*)xraw;
        f32x4 a = in[2 * i];
        f32x4 b = in[2 * i + 1];
        bf16x8 o;
        o[0] = (__bf16)a[0]; o[1] = (__bf16)a[1];
        o[2] = (__bf16)a[2]; o[3] = (__bf16)a[3];
        o[4] = (__bf16)b[0]; o[5] = (__bf16)b[1];
        o[6] = (__bf16)b[2]; o[7] = (__bf16)b[3];
        out[i] = o;
    } else {
        out[i] = ((const bf16x8*)xraw)[i];
    }
}

// ---- main GEMM: BK=64, XOR-swizzled LDS, global_load_lds both operands ----
__global__ __launch_bounds__(256) void gemm_bf16(
    const __bf16* __restrict__ xb,     // [M_TOT][IN_F] bf16 (ws)
    const __bf16* __restrict__ wb,     // [OUT_F][IN_F] bf16 (ws)
    const float*  __restrict__ w_scale,
    const float*  __restrict__ bias,
    void*         __restrict__ yraw,   // f32 or bf16 container per flag
    const int*    __restrict__ flag_p)
{
    __shared__ __align__(16) __bf16 As[BM * BK];   // 16 KiB
    __shared__ __align__(16) __bf16 Bs[BN * BK];   // 16 KiB

    const int f32w = (*flag_p != 0);

    const int t    = threadIdx.x;
    const int lane = t & 63;
    const int wv   = t >> 6;
    const int wm   = wv >> 1;
    const int wn   = wv & 1;
    const int lidx = lane & 15;
    const int q    = lane >> 4;

    // XCD-aware remap (bijection over 896): each XCD owns 14 N-tiles, M fastest.
    const int flat = blockIdx.x;
    const int xcd  = flat & 7;
    const int slot = flat >> 3;
    const int ni   = xcd * 14 + (slot >> 3);
    const int mi   = slot & 7;
    const int m0   = mi * BM;
    const int n0   = ni * BN;

    const float scale = w_scale[0];

    // DMA slots: s = i*256 + t, i in 0..3 (1024 slots of 16B per operand).
    // slot s -> row = s>>3, cg_phys = s&7; the LOGICAL 16B k-group stored
    // there is cg_log = cg_phys ^ (row&7)  (bank-conflict-free swizzle).
    const __bf16* ga[4]; const __bf16* gb[4];
    __bf16* la[4]; __bf16* lb[4];
    #pragma unroll
    for (int i = 0; i < 4; ++i) {
        const int s   = i * 256 + t;
        const int row = s >> 3;
        const int cgl = (s & 7) ^ (row & 7);
        ga[i] = xb + (size_t)(m0 + row) * IN_F + cgl * 8;
        gb[i] = wb + (size_t)(n0 + row) * IN_F + cgl * 8;
        la[i] = As + s * 8;
        lb[i] = Bs + s * 8;
    }

    const f32x4 zero4 = {0.f, 0.f, 0.f, 0.f};
    f32x4 acc[4][4];
    #pragma unroll
    for (int i = 0; i < 4; ++i)
        #pragma unroll
        for (int j = 0; j < 4; ++j)
            acc[i][j] = zero4;

    for (int kt = 0; kt < KTILES; ++kt) {
        #pragma unroll
        for (int i = 0; i < 4; ++i) {
            async_copy16(ga[i], la[i]);
            async_copy16(gb[i], lb[i]);
            ga[i] += BK; gb[i] += BK;
        }

        __syncthreads();   // drains DMA before ds_read

        #pragma unroll
        for (int ko = 0; ko < 2; ++ko) {
            bf16x8 afr[4], bfr[4];
            #pragma unroll
            for (int mt = 0; mt < 4; ++mt) {
                const int row = wm * 64 + mt * 16 + lidx;
                const int cgp = (ko * 4 + q) ^ (row & 7);   // un-swizzle
                afr[mt] = *reinterpret_cast<const bf16x8*>(As + row * BK + cgp * 8);
            }
            #pragma unroll
            for (int nt = 0; nt < 4; ++nt) {
                const int row = wn * 64 + nt * 16 + lidx;
                const int cgp = (ko * 4 + q) ^ (row & 7);
                bfr[nt] = *reinterpret_cast<const bf16x8*>(Bs + row * BK + cgp * 8);
            }
            #pragma unroll
            for (int mt = 0; mt < 4; ++mt)
                #pragma unroll
                for (int nt = 0; nt < 4; ++nt)
                    acc[mt][nt] = __builtin_amdgcn_mfma_f32_16x16x32_bf16(
                        afr[mt], bfr[nt], acc[mt][nt], 0, 0, 0);
        }

        __syncthreads();   // WAR: LDS reuse by next iter's DMA
    }

    // epilogue (R3-probe-verified C/D layout: n = lane&15, m = q*4 + reg)
    float bv[4];
    #pragma unroll
    for (int nt = 0; nt < 4; ++nt)
        bv[nt] = bias[n0 + wn * 64 + nt * 16 + lidx];

    if (f32w) {
        float* yf = (float*)yraw;
        #pragma unroll
        for (int mt = 0; mt < 4; ++mt)
            #pragma unroll
            for (int r = 0; r < 4; ++r) {
                const int m = m0 + wm * 64 + mt * 16 + q * 4 + r;
                float* yp = yf + (size_t)m * OUT_F + n0 + wn * 64 + lidx;
                #pragma unroll
                for (int nt = 0; nt < 4; ++nt)
                    yp[nt * 16] = acc[mt][nt][r] * scale + bv[nt];
            }
    } else {
        __bf16* yh = (__bf16*)yraw;
        #pragma unroll
        for (int mt = 0; mt < 4; ++mt)
            #pragma unroll
            for (int r = 0; r < 4; ++r) {
                const int m = m0 + wm * 64 + mt * 16 + q * 4 + r;
                __bf16* yp = yh + (size_t)m * OUT_F + n0 + wn * 64 + lidx;
                #pragma unroll
                for (int nt = 0; nt < 4; ++nt)
                    yp[nt * 16] = (__bf16)(acc[mt][nt][r] * scale + bv[nt]);
            }
    }
}

// ---- fallback (R6 kernel): only if ws_size can't hold cvt buffers ----
__global__ __launch_bounds__(256) void f8linear_fallback(
    const void*  __restrict__ xraw,
    const float* __restrict__ wq,
    const float* __restrict__ w_scale,
    const float* __restrict__ bias,
    void*        __restrict__ yraw,
    const int*   __restrict__ flag_p)
{
    __shared__ __align__(16) __bf16 As[BM * 40];
    __shared__ __align__(16) __bf16 Bs[BN * 40];

    const int f32w = (*flag_p != 0);
    const int t    = threadIdx.x;
    const int lane = t & 63;
    const int wv   = t >> 6;
    const int wm   = wv >> 1;
    const int wn   = wv & 1;
    const int lidx = lane & 15;
    const int q    = lane >> 4;

    const int flat = blockIdx.x;
    const int xcd  = flat & 7;
    const int slot = flat >> 3;
    const int ni   = xcd * 14 + (slot >> 3);
    const int mi   = slot & 7;
    const int m0   = mi * BM;
    const int n0   = ni * BN;

    const float scale = w_scale[0];
    const float*  xf = (const float*)xraw;
    const __bf16* xh = (const __bf16*)xraw;

    const int af_row = t >> 3;
    const int af_col = (t & 7) * 4;
    int ah_row[2], ah_cg[2];
    #pragma unroll
    for (int i = 0; i < 2; ++i) {
        const int s = i * 256 + t;
        ah_row[i] = s >> 2;
        ah_cg[i]  = s & 3;
    }
    const int b_row = t >> 3;
    const int b_col = (t & 7) * 4;

    const f32x4 zero4 = {0.f, 0.f, 0.f, 0.f};
    f32x4 acc[4][4];
    #pragma unroll
    for (int i = 0; i < 4; ++i)
        #pragma unroll
        for (int j = 0; j < 4; ++j)
            acc[i][j] = zero4;

    f32x4  aregf[4];
    bf16x8 aregh[2];
    f32x4  breg[4];
    if (f32w) {
        #pragma unroll
        for (int i = 0; i < 4; ++i)
            aregf[i] = *reinterpret_cast<const f32x4*>(
                xf + (size_t)(m0 + af_row + i * 32) * IN_F + af_col);
    } else {
        #pragma unroll
        for (int i = 0; i < 2; ++i)
            aregh[i] = *reinterpret_cast<const bf16x8*>(
                xh + (size_t)(m0 + ah_row[i]) * IN_F + ah_cg[i] * 8);
    }
    #pragma unroll
    for (int i = 0; i < 4; ++i)
        breg[i] = *reinterpret_cast<const f32x4*>(
            wq + (size_t)(n0 + i * 32 + b_row) * IN_F + b_col);

    for (int kt = 0; kt < 128; ++kt) {
        const int k0 = kt * 32;
        if (f32w) {
            #pragma unroll
            for (int i = 0; i < 4; ++i) {
                bf16x4 pk;
                pk[0] = (__bf16)aregf[i][0];
                pk[1] = (__bf16)aregf[i][1];
                pk[2] = (__bf16)aregf[i][2];
                pk[3] = (__bf16)aregf[i][3];
                *reinterpret_cast<bf16x4*>(As + (af_row + i * 32) * 40 + af_col) = pk;
            }
        } else {
            #pragma unroll
            for (int i = 0; i < 2; ++i)
                *reinterpret_cast<bf16x8*>(As + ah_row[i] * 40 + ah_cg[i] * 8) = aregh[i];
        }
        #pragma unroll
        for (int i = 0; i < 4; ++i) {
            bf16x4 pk;
            pk[0] = (__bf16)breg[i][0];
            pk[1] = (__bf16)breg[i][1];
            pk[2] = (__bf16)breg[i][2];
            pk[3] = (__bf16)breg[i][3];
            *reinterpret_cast<bf16x4*>(Bs + (i * 32 + b_row) * 40 + b_col) = pk;
        }
        __syncthreads();
        if (kt + 1 < 128) {
            const int k1 = k0 + 32;
            if (f32w) {
                #pragma unroll
                for (int i = 0; i < 4; ++i)
                    aregf[i] = *reinterpret_cast<const f32x4*>(
                        xf + (size_t)(m0 + af_row + i * 32) * IN_F + k1 + af_col);
            } else {
                #pragma unroll
                for (int i = 0; i < 2; ++i)
                    aregh[i] = *reinterpret_cast<const bf16x8*>(
                        xh + (size_t)(m0 + ah_row[i]) * IN_F + k1 + ah_cg[i] * 8);
            }
            #pragma unroll
            for (int i = 0; i < 4; ++i)
                breg[i] = *reinterpret_cast<const f32x4*>(
                    wq + (size_t)(n0 + i * 32 + b_row) * IN_F + k1 + b_col);
        }
        bf16x8 afr[4], bfr[4];
        #pragma unroll
        for (int mt = 0; mt < 4; ++mt) {
            const int row = wm * 64 + mt * 16 + lidx;
            afr[mt] = *reinterpret_cast<const bf16x8*>(As + row * 40 + q * 8);
        }
        #pragma unroll
        for (int nt = 0; nt < 4; ++nt) {
            const int row = wn * 64 + nt * 16 + lidx;
            bfr[nt] = *reinterpret_cast<const bf16x8*>(Bs + row * 40 + q * 8);
        }
        #pragma unroll
        for (int mt = 0; mt < 4; ++mt)
            #pragma unroll
            for (int nt = 0; nt < 4; ++nt)
                acc[mt][nt] = __builtin_amdgcn_mfma_f32_16x16x32_bf16(
                    afr[mt], bfr[nt], acc[mt][nt], 0, 0, 0);
        __syncthreads();
    }

    float bv[4];
    #pragma unroll
    for (int nt = 0; nt < 4; ++nt)
        bv[nt] = bias[n0 + wn * 64 + nt * 16 + lidx];

    if (f32w) {
        float* yf = (float*)yraw;
        #pragma unroll
        for (int mt = 0; mt < 4; ++mt)
            #pragma unroll
            for (int r = 0; r < 4; ++r) {
                const int m = m0 + wm * 64 + mt * 16 + q * 4 + r;
                float* yp = yf + (size_t)m * OUT_F + n0 + wn * 64 + lidx;
                #pragma unroll
                for (int nt = 0; nt < 4; ++nt)
                    yp[nt * 16] = acc[mt][nt][r] * scale + bv[nt];
            }
    } else {
        __bf16* yh = (__bf16*)yraw;
        #pragma unroll
        for (int mt = 0; mt < 4; ++mt)
            #pragma unroll
            for (int r = 0; r < 4; ++r) {
                const int m = m0 + wm * 64 + mt * 16 + q * 4 + r;
                __bf16* yp = yh + (size_t)m * OUT_F + n0 + wn * 64 + lidx;
                #pragma unroll
                for (int nt = 0; nt < 4; ++nt)
                    yp[nt * 16] = (__bf16)(acc[mt][nt][r] * scale + bv[nt]);
            }
    }
}

extern "C" void kernel_launch(void* const* d_in, const int* in_sizes, int n_in,
                              void* d_out, int out_size, void* d_ws, size_t ws_size,
                              hipStream_t stream) {
    const void* px = nullptr; const void* pw = nullptr;
    const void* ps = nullptr; const void* pb = nullptr;
    for (int i = 0; i < n_in; ++i) {
        const long sz = in_sizes[i];
        if      (sz == (long)M_TOT * IN_F) px = d_in[i];
        else if (sz == (long)OUT_F * IN_F) pw = d_in[i];
        else if (sz == 1)                  ps = d_in[i];
        else if (sz == OUT_F)              pb = d_in[i];
    }
    if (!px) px = d_in[0];
    if (!pw) pw = d_in[1];
    if (!ps) ps = d_in[2];
    if (!pb) pb = d_in[3];

    const size_t W_BYTES  = (size_t)OUT_F * IN_F * 2;   // 117,440,512
    const size_t X_OFF    = W_BYTES;
    const size_t X_BYTES  = (size_t)M_TOT * IN_F * 2;   // 8,388,608
    const size_t FLAG_OFF = X_OFF + X_BYTES;            // 125,829,120
    const int grid = (M_TOT / BM) * (OUT_F / BN);       // 896

    if (ws_size >= FLAG_OFF + 16) {
        __bf16* wbf  = (__bf16*)d_ws;
        __bf16* xbf  = (__bf16*)((char*)d_ws + X_OFF);
        int*    flag = (int*)((char*)d_ws + FLAG_OFF);

        detect_x_dtype<<<1, 256, 0, stream>>>((const uint32_t*)px, flag);
        cvt_w_kernel<<<3584, 256, 0, stream>>>((const f32x4*)pw, (bf16x8*)wbf);
        cvt_x_kernel<<<2048, 256, 0, stream>>>(px, (bf16x8*)xbf, flag);
        gemm_bf16<<<grid, 256, 0, stream>>>(
            xbf, wbf, (const float*)ps, (const float*)pb, d_out, flag);
    } else {
        int* flag = (int*)d_ws;
        detect_x_dtype<<<1, 256, 0, stream>>>((const uint32_t*)px, flag);
        f8linear_fallback<<<grid, 256, 0, stream>>>(
            px, (const float*)pw, (const float*)ps, (const float*)pb, d_out, flag);
    }
}